// Round 5
// baseline (461.617 us; speedup 1.0000x reference)
//
#include <hip/hip_runtime.h>
#include <stdint.h>

// FluteLinear: out[m,n] = sum_k x[m,k] * tables[qweight[n,k]] * scales[n, k/128]
// M=16, N=14336, K=4096, GROUP=128 (G=32). qweight = 235 MB int32.
//
// Round-7: INSTRUMENTATION round. Exact R0 pipeline (best: 317.7 us) + a
// bare-streaming probe appended after it. Four q-path variants (scattered,
// 1KB gload_lds bursts, copy-pack, NT loads) all land at ~2.2-2.5 TB/s
// effective q rate; the discriminating unknown is whether a bare contiguous
// cold read of qw is ALSO capped at ~2.2 TB/s in this environment (post-fill
// dirty hierarchy) or runs at ~6 TB/s (meaning flute_main's consumption
// geometry is at fault). The harness top-5 never shows our kernels, so the
// probe is sized for readout-by-subtraction: T_probe = total - 318.
//
// Probe: qw pass (235 MB cold) -> 256 MiB d_ws sweep (evict L3) -> qw pass
// (cold again). 726 MB, xor-reduced, asm-keepalive between passes (no fold).
// Decision rule (pre-committed):
//   total ~430-450  -> bare read fast -> attack flute_main read geometry.
//   total ~620-660  -> environment-capped -> R0 is the roofline; declare it.
//   total ~500      -> partial tax -> re-model with probe counter row.

#define K_DIM     4096
#define N_OUT     14336
#define G_CNT     32
#define KCHUNK    512
#define NKC       8
#define OUT_ELEMS (16 * 14336)

typedef _Float16 f16x8 __attribute__((ext_vector_type(8)));
typedef float    f32x4 __attribute__((ext_vector_type(4)));

union H2U { uint16_t u; _Float16 h; };
union B16 { uint32_t u[4]; f16x8 v; };

// 8 x int4 = one 128-k group of q codes for this lane
#define LOADG(dst, base)                                      \
    do {                                                      \
        _Pragma("unroll")                                     \
        for (int _s = 0; _s < 4; ++_s) {                      \
            dst[2 * _s]     = *(const int4*)((base) + _s * 32);     \
            dst[2 * _s + 1] = *(const int4*)((base) + _s * 32 + 4); \
        }                                                     \
    } while (0)

__global__ __launch_bounds__(256, 3)
void flute_main(const float* __restrict__ x,
                const int*   __restrict__ qw,
                const float* __restrict__ scales,
                const float* __restrict__ tables,
                float*       __restrict__ ws,   // [8][16][14336] partials (or out in atomic mode)
                int          use_atomic) {
    // tab2[c0 | c1<<4] = packed (f16(tables[c0]), f16(tables[c1]))
    __shared__ uint32_t tab2[256];
    {
        H2U lo, hi;
        lo.h = (_Float16)tables[threadIdx.x & 15];
        hi.h = (_Float16)tables[threadIdx.x >> 4];
        tab2[threadIdx.x] = (uint32_t)lo.u | ((uint32_t)hi.u << 16);
    }
    __syncthreads();

    const int tid  = threadIdx.x;
    const int lane = tid & 63;
    const int wave = tid >> 6;
    const int b    = blockIdx.x;
    const int kc   = b & 7;                 // 4 waves share kc -> shared x slice stays hot
    const int nt   = (b >> 3) * 4 + wave;   // 0..895
    const int n0   = nt << 4;
    const int k0   = kc * KCHUNK;

    const int row  = lane & 15;             // m for A; n-offset for B; col for D
    const int quad = lane >> 4;             // k-subgroup quad*8..quad*8+7

    const int n = n0 + row;
    const int* qp = qw + (size_t)n * K_DIM + k0 + quad * 8;

    int4 q0[8], q1[8];
    LOADG(q0, qp);                          // group 0 in flight ASAP

    // ---- preload all x as 16 f16 A-fragments (k-loop then has q-only VMEM) ----
    f16x8 a[16];
    {
        const float* xp = x + row * K_DIM + k0 + quad * 8;
        #pragma unroll
        for (int s = 0; s < 16; ++s) {
            const float4 lo = *(const float4*)(xp + s * 32);
            const float4 hi = *(const float4*)(xp + s * 32 + 4);
            f16x8 af;
            af[0] = (_Float16)lo.x; af[1] = (_Float16)lo.y;
            af[2] = (_Float16)lo.z; af[3] = (_Float16)lo.w;
            af[4] = (_Float16)hi.x; af[5] = (_Float16)hi.y;
            af[6] = (_Float16)hi.z; af[7] = (_Float16)hi.w;
            a[s] = af;
        }
    }
    const float4 sc = *(const float4*)(scales + n * G_CNT + kc * 4);

    auto dequant_group = [&](const int4* qb, const f16x8* af) {
        f32x4 accg = {0.f, 0.f, 0.f, 0.f};
        #pragma unroll
        for (int s = 0; s < 4; ++s) {
            const int4 qa = qb[2 * s];
            const int4 qc = qb[2 * s + 1];
            B16 bf;
            bf.u[0] = tab2[qa.x + (qa.y << 4)];
            bf.u[1] = tab2[qa.z + (qa.w << 4)];
            bf.u[2] = tab2[qc.x + (qc.y << 4)];
            bf.u[3] = tab2[qc.z + (qc.w << 4)];
            accg = __builtin_amdgcn_mfma_f32_16x16x32_f16(af[s], bf.v, accg, 0, 0, 0);
        }
        return accg;
    };

    // ---- 2-stage pipeline over the 4 scale groups ----
    f32x4 acc = {0.f, 0.f, 0.f, 0.f};
    f32x4 t;
    LOADG(q1, qp + 128);                    // group 1 in flight
    t = dequant_group(q0, a + 0);           // consume g0 (vmcnt(8): g1 stays out)
    acc[0] += sc.x * t[0]; acc[1] += sc.x * t[1]; acc[2] += sc.x * t[2]; acc[3] += sc.x * t[3];
    LOADG(q0, qp + 256);                    // group 2 in flight
    t = dequant_group(q1, a + 4);
    acc[0] += sc.y * t[0]; acc[1] += sc.y * t[1]; acc[2] += sc.y * t[2]; acc[3] += sc.y * t[3];
    LOADG(q1, qp + 384);                    // group 3 in flight
    t = dequant_group(q0, a + 8);
    acc[0] += sc.z * t[0]; acc[1] += sc.z * t[1]; acc[2] += sc.z * t[2]; acc[3] += sc.z * t[3];
    t = dequant_group(q1, a + 12);
    acc[0] += sc.w * t[0]; acc[1] += sc.w * t[1]; acc[2] += sc.w * t[2]; acc[3] += sc.w * t[3];

    // ---- D layout: col = lane&15 (= n-n0), rowD = quad*4 + r (= m) ----
    if (use_atomic) {
        float* op = ws + n;                 // ws == out here
        #pragma unroll
        for (int r = 0; r < 4; ++r) atomicAdd(op + (quad * 4 + r) * N_OUT, acc[r]);
    } else {
        float* op = ws + (size_t)kc * OUT_ELEMS + n;
        #pragma unroll
        for (int r = 0; r < 4; ++r) op[(size_t)(quad * 4 + r) * N_OUT] = acc[r];
    }
}

__global__ __launch_bounds__(256)
void flute_reduce(const float4* __restrict__ ws, float4* __restrict__ out) {
    const int i = blockIdx.x * 256 + threadIdx.x;   // 0..57343 (float4 index)
    float4 s = ws[i];
    #pragma unroll
    for (int kc = 1; kc < NKC; ++kc) {
        const float4 t = ws[(size_t)kc * (OUT_ELEMS / 4) + i];
        s.x += t.x; s.y += t.y; s.z += t.z; s.w += t.w;
    }
    out[i] = s;
}

// ---- PROBE: bare contiguous streaming rate in this environment ----
// pass1: qw (235 MB, cold). pass2: 256 MiB of untouched ws (evicts L3).
// pass3: qw again (cold again). T_probe = total - 318 us baseline.
__global__ __launch_bounds__(256)
void qprobe(const int4* __restrict__ qw, const int4* __restrict__ wsbig,
            float* __restrict__ scratch) {
    const size_t nq = (size_t)N_OUT * K_DIM / 4;          // 14,680,064 int4
    const size_t nw = (size_t)256 * 1024 * 1024 / 16;     // 16,777,216 int4
    const size_t t0 = (size_t)blockIdx.x * 256 + threadIdx.x;
    const size_t gs = (size_t)gridDim.x * 256;
    int acc = 0;
    for (size_t i = t0; i < nq; i += gs) {                // qw cold
        const int4 v = qw[i];
        acc ^= v.x ^ v.y ^ v.z ^ v.w;
    }
    asm volatile("" : "+v"(acc));                         // no cross-pass fold
    for (size_t i = t0; i < nw; i += gs) {                // L3 evict sweep
        const int4 v = wsbig[i];
        acc ^= v.x ^ v.y ^ v.z ^ v.w;
    }
    asm volatile("" : "+v"(acc));
    for (size_t i = t0; i < nq; i += gs) {                // qw cold again
        const int4 v = qw[i];
        acc ^= v.x ^ v.y ^ v.z ^ v.w;
    }
    scratch[t0] = (float)acc;
}

extern "C" void kernel_launch(void* const* d_in, const int* in_sizes, int n_in,
                              void* d_out, int out_size, void* d_ws, size_t ws_size,
                              hipStream_t stream) {
    const float* x      = (const float*)d_in[0];
    const int*   qw     = (const int*)  d_in[1];
    const float* scales = (const float*)d_in[2];
    const float* tables = (const float*)d_in[3];
    float*       out    = (float*)d_out;

    const size_t part_bytes  = (size_t)NKC * OUT_ELEMS * sizeof(float);   // 7.34 MB
    const size_t probe_bytes = (size_t)2048 * 256 * sizeof(float);        // 2 MB
    dim3 grid(1792), block(256);

    if (ws_size >= part_bytes + probe_bytes) {
        float* ws = (float*)d_ws;
        flute_main<<<grid, block, 0, stream>>>(x, qw, scales, tables, ws, 0);
        flute_reduce<<<dim3(OUT_ELEMS / 4 / 256), block, 0, stream>>>(
            (const float4*)ws, (float4*)out);
        // probe AFTER the pipeline so main/reduce timings match R0 exactly
        float* scratch = ws + part_bytes / sizeof(float);
        const int4* wsbig = (ws_size >= (size_t)(512 + 256) * 1024 * 1024)
                          ? (const int4*)((const char*)d_ws + ((size_t)512 << 20))
                          : (const int4*)qw;   // degrade: warm re-read
        qprobe<<<dim3(2048), block, 0, stream>>>((const int4*)qw, wsbig, scratch);
    } else {
        // fallback: accumulate directly into out (needs zeroed out)
        (void)hipMemsetAsync(out, 0, (size_t)out_size * sizeof(float), stream);
        flute_main<<<grid, block, 0, stream>>>(x, qw, scales, tables, out, 1);
    }
}